// Round 6
// baseline (258.459 us; speedup 1.0000x reference)
//
#include <hip/hip_runtime.h>
#include <hip/hip_bf16.h>

#define NN 100000
#define CC 128
#define KK 32
#define BB 64

typedef __bf16 bf16x8 __attribute__((ext_vector_type(8)));
typedef float  f32x4  __attribute__((ext_vector_type(4)));

__device__ __forceinline__ unsigned short f2bf(float v) {       // RNE bf16
    union { float f; unsigned u; } a; a.f = v;
    unsigned r = a.u + 0x7FFF + ((a.u >> 16) & 1);
    return (unsigned short)(r >> 16);
}
__device__ __forceinline__ float bf2f(unsigned short h) {
    union { unsigned u; float f; } a; a.u = ((unsigned)h) << 16;
    return a.f;
}

// ---------------------------------------------------------------------------
// Kernel 1 (prep): per-graph bounds + zero slice-counters + W1 -> bf16 hi/lo
// MFMA B-fragments.  w1f[split 2][kt 4][nt 8][lane 64][j 8]:
//   (kt,nt,lane,j) = W1[kt*32 + (lane>>4)*8 + j][nt*16 + (lane&15)]
// 8 blocks x 256 threads.
// ---------------------------------------------------------------------------
__global__ __launch_bounds__(256) void hp_prep(const int* __restrict__ batch,
                                               const float* __restrict__ W1,
                                               int* __restrict__ bounds,
                                               int* __restrict__ counters,
                                               unsigned short* __restrict__ w1f) {
    if (blockIdx.x == 0) {
        if (threadIdx.x <= BB) {
            const int b = threadIdx.x;
            int lo = 0, hi = NN;
            while (lo < hi) {
                const int mid = (lo + hi) >> 1;
                if (batch[mid] < b) lo = mid + 1; else hi = mid;
            }
            bounds[b] = lo;
        }
        if (threadIdx.x >= 128 && threadIdx.x < 128 + BB)
            counters[threadIdx.x - 128] = 0;
    }
    const int t = blockIdx.x * 256 + threadIdx.x;
    for (int idx = t; idx < 16384; idx += 2048) {
        const int j    = idx & 7;
        const int lane = (idx >> 3) & 63;
        const int nt   = (idx >> 9) & 7;
        const int kt   = idx >> 12;
        const int k = kt * 32 + (lane >> 4) * 8 + j;
        const int n = nt * 16 + (lane & 15);
        const float w = W1[k * CC + n];
        const unsigned short h = f2bf(w);
        w1f[idx]         = h;
        w1f[16384 + idx] = f2bf(w - bf2f(h));
    }
}

// ---------------------------------------------------------------------------
// Kernel 2: h = relu(x@W1+b1) via split-bf16 MFMA; s = softmax(h@W2+b2).
// Block = 32 nodes (3125 blocks, NN = 32*3125 exactly), 256 threads, 4 waves.
//  stage:   x -> bf16 hi/lo A-frags in LDS (2 frags/thread).
//  phase 1: wave w owns n-tiles {2w,2w+1}: 48 mfma_f32_16x16x32_bf16
//           (xh*wh + xl*wh + xh*wl); W frags coalesced from global (L2-hot).
//  epilog:  bias+relu -> hs[32][130] f32 (overlays dead xa).
//  phase 2: lane = (node = l&31, khalf = l>>5); wave w computes 4 logits
//           k = khalf*16 + 4w + j  (all 64 lanes busy; W2 via L1 vector loads).
//  phase 3: softmax via 2-round LDS max/sum combine; every lane stores 4 s.
// LDS: max(xa 16K, hs 16.6K) + red 1K = 17.7 KB; __launch_bounds__(256,8)
// caps VGPR at 64 -> target 8 blocks/CU (32 waves).
// ---------------------------------------------------------------------------
__global__ __launch_bounds__(256, 8) void hp_mlp(
    const float* __restrict__ x,
    const unsigned short* __restrict__ w1f,
    const float* __restrict__ b1,
    const float* __restrict__ W2,
    const float* __restrict__ b2,
    float* __restrict__ s_out)
{
    __shared__ __align__(16) char uni[16640];     // xa (16384 B) / hs (16640 B)
    __shared__ float redm[4][32];
    __shared__ float reds[4][32];

    unsigned short* xa = (unsigned short*)uni;    // [split][q=mt*4+kt][lane][8]
    float*          hs = (float*)uni;             // [node][130]

    const int t    = threadIdx.x;
    const int wave = __builtin_amdgcn_readfirstlane(t >> 6);
    const int lane = t & 63;
    const int base = blockIdx.x * 32;

    // ---- stage x -> bf16 hi/lo A-frags (thread does mt = 0,1; kt = wave) ----
    #pragma unroll
    for (int mt = 0; mt < 2; ++mt) {
        const int q  = mt * 4 + wave;
        const int n  = base + mt * 16 + (lane & 15);
        const int ck = wave * 32 + (lane >> 4) * 8;
        const float4 va = *(const float4*)(x + (size_t)n * CC + ck);
        const float4 vb = *(const float4*)(x + (size_t)n * CC + ck + 4);
        const float v[8] = {va.x, va.y, va.z, va.w, vb.x, vb.y, vb.z, vb.w};
        unsigned short hi[8], lo[8];
        #pragma unroll
        for (int j = 0; j < 8; ++j) {
            hi[j] = f2bf(v[j]);
            lo[j] = f2bf(v[j] - bf2f(hi[j]));
        }
        unsigned short* d0 = xa + (q * 64 + lane) * 8;
        unsigned short* d1 = d0 + 4096;
        *(ushort4*)(d0)     = make_ushort4(hi[0], hi[1], hi[2], hi[3]);
        *(ushort4*)(d0 + 4) = make_ushort4(hi[4], hi[5], hi[6], hi[7]);
        *(ushort4*)(d1)     = make_ushort4(lo[0], lo[1], lo[2], lo[3]);
        *(ushort4*)(d1 + 4) = make_ushort4(lo[4], lo[5], lo[6], lo[7]);
    }
    __syncthreads();

    // ---- phase 1: MFMA; wave owns n-tiles 2w, 2w+1 ----
    f32x4 acc[2][2];
    #pragma unroll
    for (int mt = 0; mt < 2; ++mt)
        #pragma unroll
        for (int nl = 0; nl < 2; ++nl)
            acc[mt][nl] = (f32x4){0.f, 0.f, 0.f, 0.f};

    #pragma unroll
    for (int kt = 0; kt < 4; ++kt) {
        bf16x8 ah[2], al[2];
        #pragma unroll
        for (int mt = 0; mt < 2; ++mt) {
            ah[mt] = *(const bf16x8*)(xa + ((mt * 4 + kt) * 64 + lane) * 8);
            al[mt] = *(const bf16x8*)(xa + 4096 + ((mt * 4 + kt) * 64 + lane) * 8);
        }
        #pragma unroll
        for (int nl = 0; nl < 2; ++nl) {
            const int nt = 2 * wave + nl;
            const bf16x8 wh = *(const bf16x8*)(w1f + ((kt * 8 + nt) * 64 + lane) * 8);
            const bf16x8 wl = *(const bf16x8*)(w1f + 16384 + ((kt * 8 + nt) * 64 + lane) * 8);
            #pragma unroll
            for (int mt = 0; mt < 2; ++mt) {
                acc[mt][nl] = __builtin_amdgcn_mfma_f32_16x16x32_bf16(ah[mt], wh, acc[mt][nl], 0, 0, 0);
                acc[mt][nl] = __builtin_amdgcn_mfma_f32_16x16x32_bf16(al[mt], wh, acc[mt][nl], 0, 0, 0);
                acc[mt][nl] = __builtin_amdgcn_mfma_f32_16x16x32_bf16(ah[mt], wl, acc[mt][nl], 0, 0, 0);
            }
        }
    }
    __syncthreads();                               // xa dead; hs overlays

    // ---- epilogue: bias + relu -> hs[node][130] ----
    #pragma unroll
    for (int nl = 0; nl < 2; ++nl) {
        const int c = (2 * wave + nl) * 16 + (lane & 15);
        const float bv = b1[c];
        #pragma unroll
        for (int mt = 0; mt < 2; ++mt)
            #pragma unroll
            for (int r = 0; r < 4; ++r) {
                const int node = mt * 16 + (lane >> 4) * 4 + r;
                hs[node * 130 + c] = fmaxf(acc[mt][nl][r] + bv, 0.f);
            }
    }
    __syncthreads();

    // ---- phase 2: 4 logits per lane; node = l&31, k = (l>>5)*16 + 4w + j ----
    const int node = lane & 31;
    const int koff = ((lane >> 5) << 4) + wave * 4;
    float4 bv2 = *(const float4*)(b2 + koff);
    float lg[4] = {bv2.x, bv2.y, bv2.z, bv2.w};
    const float* hrow = hs + node * 130;
    #pragma unroll 4
    for (int c = 0; c < CC; c += 2) {
        const float2 hv = *(const float2*)(hrow + c);
        const float4 w0 = *(const float4*)(W2 + c * KK + koff);
        const float4 w1 = *(const float4*)(W2 + (c + 1) * KK + koff);
        lg[0] = fmaf(hv.x, w0.x, lg[0]); lg[1] = fmaf(hv.x, w0.y, lg[1]);
        lg[2] = fmaf(hv.x, w0.z, lg[2]); lg[3] = fmaf(hv.x, w0.w, lg[3]);
        lg[0] = fmaf(hv.y, w1.x, lg[0]); lg[1] = fmaf(hv.y, w1.y, lg[1]);
        lg[2] = fmaf(hv.y, w1.z, lg[2]); lg[3] = fmaf(hv.y, w1.w, lg[3]);
    }

    // ---- phase 3: softmax (2-round LDS combine), all lanes store ----
    float m = fmaxf(fmaxf(lg[0], lg[1]), fmaxf(lg[2], lg[3]));
    m = fmaxf(m, __shfl_xor(m, 32));
    if (lane < 32) redm[wave][lane] = m;
    __syncthreads();
    const float M = fmaxf(fmaxf(redm[0][node], redm[1][node]),
                          fmaxf(redm[2][node], redm[3][node]));
    const float e0 = __expf(lg[0] - M);
    const float e1 = __expf(lg[1] - M);
    const float e2 = __expf(lg[2] - M);
    const float e3 = __expf(lg[3] - M);
    float sp = (e0 + e1) + (e2 + e3);
    sp += __shfl_xor(sp, 32);
    if (lane < 32) reds[wave][lane] = sp;
    __syncthreads();
    const float S = (reds[0][node] + reds[1][node]) + (reds[2][node] + reds[3][node]);
    const float inv = 1.f / S;
    *(float4*)(s_out + (size_t)(base + node) * KK + koff) =
        make_float4(e0 * inv, e1 * inv, e2 * inv, e3 * inv);
}

// ---------------------------------------------------------------------------
// Kernel 3: pooling + fused reduce. Block = (graph b, slice p); 256 threads;
// thread owns a 4k x 4c register tile. Partial tiles -> ws; last-arriving
// block per graph (device-scope counter) sums the slices and writes out.
// ---------------------------------------------------------------------------
__global__ __launch_bounds__(256) void hp_pool(
    const float* __restrict__ x,
    const float* __restrict__ s,
    const int* __restrict__ bounds,
    float* __restrict__ part,
    int* __restrict__ counters,
    float* __restrict__ out,
    int nslices)
{
    __shared__ int sflag;

    const int b = blockIdx.x / nslices;
    const int p = blockIdx.x - b * nslices;
    const int t = threadIdx.x;

    const int gs  = bounds[b];
    const int cnt = bounds[b + 1] - gs;
    const int n0  = gs + (int)(((long long)cnt * p) / nslices);
    const int n1  = gs + (int)(((long long)cnt * (p + 1)) / nslices);

    const int k0 = (t >> 5) * 4;
    const int c0 = (t & 31) * 4;

    float a4[4][4] = {{0.f}};

    #pragma unroll 4
    for (int n = n0; n < n1; ++n) {
        const float4 xv = *(const float4*)(x + (size_t)n * CC + c0);
        const float4 sv = *(const float4*)(s + (size_t)n * KK + k0);
        a4[0][0] = fmaf(sv.x, xv.x, a4[0][0]); a4[0][1] = fmaf(sv.x, xv.y, a4[0][1]);
        a4[0][2] = fmaf(sv.x, xv.z, a4[0][2]); a4[0][3] = fmaf(sv.x, xv.w, a4[0][3]);
        a4[1][0] = fmaf(sv.y, xv.x, a4[1][0]); a4[1][1] = fmaf(sv.y, xv.y, a4[1][1]);
        a4[1][2] = fmaf(sv.y, xv.z, a4[1][2]); a4[1][3] = fmaf(sv.y, xv.w, a4[1][3]);
        a4[2][0] = fmaf(sv.z, xv.x, a4[2][0]); a4[2][1] = fmaf(sv.z, xv.y, a4[2][1]);
        a4[2][2] = fmaf(sv.z, xv.z, a4[2][2]); a4[2][3] = fmaf(sv.z, xv.w, a4[2][3]);
        a4[3][0] = fmaf(sv.w, xv.x, a4[3][0]); a4[3][1] = fmaf(sv.w, xv.y, a4[3][1]);
        a4[3][2] = fmaf(sv.w, xv.z, a4[3][2]); a4[3][3] = fmaf(sv.w, xv.w, a4[3][3]);
    }

    float* op = part + (size_t)blockIdx.x * KK * CC;
    #pragma unroll
    for (int a = 0; a < 4; ++a)
        *(float4*)&op[(k0 + a) * CC + c0] =
            make_float4(a4[a][0], a4[a][1], a4[a][2], a4[a][3]);

    __threadfence();                               // release partial tile
    if (t == 0) {
        const int old = atomicAdd(counters + b, 1);
        sflag = (old == nslices - 1);
    }
    __syncthreads();
    if (sflag) {                                   // last block: reduce + write
        __threadfence();                           // acquire all partials
        const float* pp = part + (size_t)b * nslices * KK * CC;
        #pragma unroll
        for (int a = 0; a < 4; ++a) {
            const int j = (k0 + a) * CC + c0;
            float4 r = make_float4(0.f, 0.f, 0.f, 0.f);
            for (int q = 0; q < nslices; ++q) {
                const float4 v = *(const float4*)(pp + (size_t)q * KK * CC + j);
                r.x += v.x; r.y += v.y; r.z += v.z; r.w += v.w;
            }
            *(float4*)(out + (size_t)b * KK * CC + j) = r;
        }
    }
}

// ---------------------------------------------------------------------------
extern "C" void kernel_launch(void* const* d_in, const int* in_sizes, int n_in,
                              void* d_out, int out_size, void* d_ws, size_t ws_size,
                              hipStream_t stream) {
    const float* x     = (const float*)d_in[0];
    const int*   batch = (const int*)d_in[1];
    const float* W1    = (const float*)d_in[2];
    const float* b1    = (const float*)d_in[3];
    const float* W2    = (const float*)d_in[4];
    const float* b2    = (const float*)d_in[5];

    float* out = (float*)d_out;                    // [B,K,C] = 262144 floats
    float* s   = out + (size_t)BB * KK * CC;       // [N,K]   = 3200000 floats

    int*            bounds   = (int*)d_ws;                         // 65 ints
    int*            counters = (int*)((char*)d_ws + 512);          // 64 ints
    unsigned short* w1f      = (unsigned short*)((char*)d_ws + 1024); // 64 KB
    float*          part     = (float*)((char*)d_ws + 1024 + 65536);

    int nslices = 8;                               // 8 MB of partials
    if (ws_size < 1024 + 65536 + (size_t)BB * 8 * KK * CC * 4)
        nslices = 4;

    hp_prep<<<8, 256, 0, stream>>>(batch, W1, bounds, counters, w1f);
    hp_mlp<<<NN / 32, 256, 0, stream>>>(x, w1f, b1, W2, b2, s);
    hp_pool<<<BB * nslices, 256, 0, stream>>>(x, s, bounds, part, counters, out, nslices);
}

// Round 7
// 191.014 us; speedup vs baseline: 1.3531x; 1.3531x over previous
//
#include <hip/hip_runtime.h>
#include <hip/hip_bf16.h>

#define NN 100000
#define CC 128
#define KK 32
#define BB 64

typedef __bf16 bf16x8 __attribute__((ext_vector_type(8)));
typedef float  f32x4  __attribute__((ext_vector_type(4)));

__device__ __forceinline__ unsigned short f2bf(float v) {       // RNE bf16
    union { float f; unsigned u; } a; a.f = v;
    unsigned r = a.u + 0x7FFF + ((a.u >> 16) & 1);
    return (unsigned short)(r >> 16);
}
__device__ __forceinline__ float bf2f(unsigned short h) {
    union { unsigned u; float f; } a; a.u = ((unsigned)h) << 16;
    return a.f;
}

// ---------------------------------------------------------------------------
// Kernel 1 (prep): per-graph bounds + W1 -> bf16 hi/lo MFMA B-fragments.
// w1f[split 2][kt 4][nt 8][lane 64][j 8]:
//   (kt,nt,lane,j) = W1[kt*32 + (lane>>4)*8 + j][nt*16 + (lane&15)]
// 8 blocks x 256 threads.
// ---------------------------------------------------------------------------
__global__ __launch_bounds__(256) void hp_prep(const int* __restrict__ batch,
                                               const float* __restrict__ W1,
                                               int* __restrict__ bounds,
                                               unsigned short* __restrict__ w1f) {
    if (blockIdx.x == 0 && threadIdx.x <= BB) {
        const int b = threadIdx.x;
        int lo = 0, hi = NN;
        while (lo < hi) {
            const int mid = (lo + hi) >> 1;
            if (batch[mid] < b) lo = mid + 1; else hi = mid;
        }
        bounds[b] = lo;
    }
    const int t = blockIdx.x * 256 + threadIdx.x;
    for (int idx = t; idx < 16384; idx += 2048) {
        const int j    = idx & 7;
        const int lane = (idx >> 3) & 63;
        const int nt   = (idx >> 9) & 7;
        const int kt   = idx >> 12;
        const int k = kt * 32 + (lane >> 4) * 8 + j;
        const int n = nt * 16 + (lane & 15);
        const float w = W1[k * CC + n];
        const unsigned short h = f2bf(w);
        w1f[idx]         = h;
        w1f[16384 + idx] = f2bf(w - bf2f(h));
    }
}

// ---------------------------------------------------------------------------
// Kernel 2: h = relu(x@W1+b1) via split-bf16 MFMA; s = softmax(h@W2+b2).
// Block = 32 nodes (3125 blocks), 256 threads, 4 waves.
// Same structure as round 6 but __launch_bounds__(256,6): ~85 VGPR budget
// (round-6's (256,8) => 64-VGPR cap likely spilled the staging temporaries).
// LDS 17.7 KB => 6 blocks/CU (24 waves) at the VGPR bound.
// ---------------------------------------------------------------------------
__global__ __launch_bounds__(256, 6) void hp_mlp(
    const float* __restrict__ x,
    const unsigned short* __restrict__ w1f,
    const float* __restrict__ b1,
    const float* __restrict__ W2,
    const float* __restrict__ b2,
    float* __restrict__ s_out)
{
    __shared__ __align__(16) char uni[16640];     // xa (16384 B) / hs (16640 B)
    __shared__ float redm[4][32];
    __shared__ float reds[4][32];

    unsigned short* xa = (unsigned short*)uni;    // [split][q=mt*4+kt][lane][8]
    float*          hs = (float*)uni;             // [node][130]

    const int t    = threadIdx.x;
    const int wave = __builtin_amdgcn_readfirstlane(t >> 6);
    const int lane = t & 63;
    const int base = blockIdx.x * 32;

    // ---- stage x -> bf16 hi/lo A-frags (thread does mt = 0,1; kt = wave) ----
    #pragma unroll
    for (int mt = 0; mt < 2; ++mt) {
        const int q  = mt * 4 + wave;
        const int n  = base + mt * 16 + (lane & 15);
        const int ck = wave * 32 + (lane >> 4) * 8;
        const float4 va = *(const float4*)(x + (size_t)n * CC + ck);
        const float4 vb = *(const float4*)(x + (size_t)n * CC + ck + 4);
        const float v[8] = {va.x, va.y, va.z, va.w, vb.x, vb.y, vb.z, vb.w};
        unsigned short hi[8], lo[8];
        #pragma unroll
        for (int j = 0; j < 8; ++j) {
            hi[j] = f2bf(v[j]);
            lo[j] = f2bf(v[j] - bf2f(hi[j]));
        }
        unsigned short* d0 = xa + (q * 64 + lane) * 8;
        unsigned short* d1 = d0 + 4096;
        *(ushort4*)(d0)     = make_ushort4(hi[0], hi[1], hi[2], hi[3]);
        *(ushort4*)(d0 + 4) = make_ushort4(hi[4], hi[5], hi[6], hi[7]);
        *(ushort4*)(d1)     = make_ushort4(lo[0], lo[1], lo[2], lo[3]);
        *(ushort4*)(d1 + 4) = make_ushort4(lo[4], lo[5], lo[6], lo[7]);
    }
    __syncthreads();

    // ---- phase 1: MFMA; wave owns n-tiles 2w, 2w+1 ----
    f32x4 acc[2][2];
    #pragma unroll
    for (int mt = 0; mt < 2; ++mt)
        #pragma unroll
        for (int nl = 0; nl < 2; ++nl)
            acc[mt][nl] = (f32x4){0.f, 0.f, 0.f, 0.f};

    #pragma unroll
    for (int kt = 0; kt < 4; ++kt) {
        bf16x8 ah[2], al[2];
        #pragma unroll
        for (int mt = 0; mt < 2; ++mt) {
            ah[mt] = *(const bf16x8*)(xa + ((mt * 4 + kt) * 64 + lane) * 8);
            al[mt] = *(const bf16x8*)(xa + 4096 + ((mt * 4 + kt) * 64 + lane) * 8);
        }
        #pragma unroll
        for (int nl = 0; nl < 2; ++nl) {
            const int nt = 2 * wave + nl;
            const bf16x8 wh = *(const bf16x8*)(w1f + ((kt * 8 + nt) * 64 + lane) * 8);
            const bf16x8 wl = *(const bf16x8*)(w1f + 16384 + ((kt * 8 + nt) * 64 + lane) * 8);
            #pragma unroll
            for (int mt = 0; mt < 2; ++mt) {
                acc[mt][nl] = __builtin_amdgcn_mfma_f32_16x16x32_bf16(ah[mt], wh, acc[mt][nl], 0, 0, 0);
                acc[mt][nl] = __builtin_amdgcn_mfma_f32_16x16x32_bf16(al[mt], wh, acc[mt][nl], 0, 0, 0);
                acc[mt][nl] = __builtin_amdgcn_mfma_f32_16x16x32_bf16(ah[mt], wl, acc[mt][nl], 0, 0, 0);
            }
        }
    }
    __syncthreads();                               // xa dead; hs overlays

    // ---- epilogue: bias + relu -> hs[node][130] ----
    #pragma unroll
    for (int nl = 0; nl < 2; ++nl) {
        const int c = (2 * wave + nl) * 16 + (lane & 15);
        const float bv = b1[c];
        #pragma unroll
        for (int mt = 0; mt < 2; ++mt)
            #pragma unroll
            for (int r = 0; r < 4; ++r) {
                const int node = mt * 16 + (lane >> 4) * 4 + r;
                hs[node * 130 + c] = fmaxf(acc[mt][nl][r] + bv, 0.f);
            }
    }
    __syncthreads();

    // ---- phase 2: 4 logits per lane; node = l&31, k = (l>>5)*16 + 4w + j ----
    const int node = lane & 31;
    const int koff = ((lane >> 5) << 4) + wave * 4;
    float4 bv2 = *(const float4*)(b2 + koff);
    float lg[4] = {bv2.x, bv2.y, bv2.z, bv2.w};
    const float* hrow = hs + node * 130;
    #pragma unroll 4
    for (int c = 0; c < CC; c += 2) {
        const float2 hv = *(const float2*)(hrow + c);
        const float4 w0 = *(const float4*)(W2 + c * KK + koff);
        const float4 w1 = *(const float4*)(W2 + (c + 1) * KK + koff);
        lg[0] = fmaf(hv.x, w0.x, lg[0]); lg[1] = fmaf(hv.x, w0.y, lg[1]);
        lg[2] = fmaf(hv.x, w0.z, lg[2]); lg[3] = fmaf(hv.x, w0.w, lg[3]);
        lg[0] = fmaf(hv.y, w1.x, lg[0]); lg[1] = fmaf(hv.y, w1.y, lg[1]);
        lg[2] = fmaf(hv.y, w1.z, lg[2]); lg[3] = fmaf(hv.y, w1.w, lg[3]);
    }

    // ---- phase 3: softmax (2-round LDS combine), all lanes store ----
    float m = fmaxf(fmaxf(lg[0], lg[1]), fmaxf(lg[2], lg[3]));
    m = fmaxf(m, __shfl_xor(m, 32));
    if (lane < 32) redm[wave][lane] = m;
    __syncthreads();
    const float M = fmaxf(fmaxf(redm[0][node], redm[1][node]),
                          fmaxf(redm[2][node], redm[3][node]));
    const float e0 = __expf(lg[0] - M);
    const float e1 = __expf(lg[1] - M);
    const float e2 = __expf(lg[2] - M);
    const float e3 = __expf(lg[3] - M);
    float sp = (e0 + e1) + (e2 + e3);
    sp += __shfl_xor(sp, 32);
    if (lane < 32) reds[wave][lane] = sp;
    __syncthreads();
    const float S = (reds[0][node] + reds[1][node]) + (reds[2][node] + reds[3][node]);
    const float inv = 1.f / S;
    *(float4*)(s_out + (size_t)(base + node) * KK + koff) =
        make_float4(e0 * inv, e1 * inv, e2 * inv, e3 * inv);
}

// ---------------------------------------------------------------------------
// Kernel 3: partial pooling, panel-staged. Block = (graph b, slice p of
// nslices); 256 threads; thread owns a 4k x 4c register tile. 8-node panels
// staged in LDS (x: one coalesced wave-instr per panel; s: 64 threads) kill
// the 8x VMEM broadcast redundancy of per-lane streaming. LDS 5.3 KB,
// ~40 VGPR -> 8 blocks/CU at nslices=32 (2048 blocks): latency hidden.
// ---------------------------------------------------------------------------
__global__ __launch_bounds__(256, 8) void hp_pool(
    const float* __restrict__ x,
    const float* __restrict__ s,
    const int* __restrict__ bounds,
    float* __restrict__ part,
    int nslices)
{
    __shared__ float xs[8][CC];           // stride 128: write/read conflict-free
    __shared__ float ss[8][36];           // 16B-aligned rows

    const int b = blockIdx.x / nslices;
    const int p = blockIdx.x - b * nslices;
    const int t = threadIdx.x;

    const int gs  = bounds[b];
    const int cnt = bounds[b + 1] - gs;
    const int n0  = gs + (int)(((long long)cnt * p) / nslices);
    const int n1  = gs + (int)(((long long)cnt * (p + 1)) / nslices);

    const int k0 = (t >> 5) * 4;
    const int c0 = (t & 31) * 4;

    float a4[4][4] = {{0.f}};

    for (int nb = n0; nb < n1; nb += 8) {
        const int m = min(8, n1 - nb);
        __syncthreads();                   // previous panel consumed
        {
            const int r = t >> 5, cf = t & 31;
            if (r < m)
                *(float4*)&xs[r][cf * 4] = ((const float4*)x)[(size_t)(nb + r) * 32 + cf];
            if (t < 64) {
                const int r2 = t >> 3, kf = t & 7;
                if (r2 < m)
                    *(float4*)&ss[r2][kf * 4] = ((const float4*)s)[(size_t)(nb + r2) * 8 + kf];
            }
        }
        __syncthreads();

        for (int i = 0; i < m; ++i) {
            const float4 xv = *(const float4*)&xs[i][c0];
            const float4 sv = *(const float4*)&ss[i][k0];
            a4[0][0] = fmaf(sv.x, xv.x, a4[0][0]); a4[0][1] = fmaf(sv.x, xv.y, a4[0][1]);
            a4[0][2] = fmaf(sv.x, xv.z, a4[0][2]); a4[0][3] = fmaf(sv.x, xv.w, a4[0][3]);
            a4[1][0] = fmaf(sv.y, xv.x, a4[1][0]); a4[1][1] = fmaf(sv.y, xv.y, a4[1][1]);
            a4[1][2] = fmaf(sv.y, xv.z, a4[1][2]); a4[1][3] = fmaf(sv.y, xv.w, a4[1][3]);
            a4[2][0] = fmaf(sv.z, xv.x, a4[2][0]); a4[2][1] = fmaf(sv.z, xv.y, a4[2][1]);
            a4[2][2] = fmaf(sv.z, xv.z, a4[2][2]); a4[2][3] = fmaf(sv.z, xv.w, a4[2][3]);
            a4[3][0] = fmaf(sv.w, xv.x, a4[3][0]); a4[3][1] = fmaf(sv.w, xv.y, a4[3][1]);
            a4[3][2] = fmaf(sv.w, xv.z, a4[3][2]); a4[3][3] = fmaf(sv.w, xv.w, a4[3][3]);
        }
    }

    float* op = part + (size_t)blockIdx.x * KK * CC;
    #pragma unroll
    for (int a = 0; a < 4; ++a)
        *(float4*)&op[(k0 + a) * CC + c0] =
            make_float4(a4[a][0], a4[a][1], a4[a][2], a4[a][3]);
}

// ---------------------------------------------------------------------------
// Kernel 4: out[b] = sum of the nslices partial tiles.
// ---------------------------------------------------------------------------
__global__ __launch_bounds__(256) void hp_reduce(const float* __restrict__ part,
                                                 float* __restrict__ out,
                                                 int nslices) {
    const int i = (blockIdx.x * 256 + threadIdx.x) * 4;
    if (i < BB * KK * CC) {
        const int b = i >> 12;
        const int j = i & 4095;
        const float* pp = part + (size_t)b * nslices * 4096 + j;
        float4 r = make_float4(0.f, 0.f, 0.f, 0.f);
        for (int q = 0; q < nslices; ++q) {
            const float4 v = *(const float4*)(pp + (size_t)q * 4096);
            r.x += v.x; r.y += v.y; r.z += v.z; r.w += v.w;
        }
        *(float4*)(out + i) = r;
    }
}

// ---------------------------------------------------------------------------
extern "C" void kernel_launch(void* const* d_in, const int* in_sizes, int n_in,
                              void* d_out, int out_size, void* d_ws, size_t ws_size,
                              hipStream_t stream) {
    const float* x     = (const float*)d_in[0];
    const int*   batch = (const int*)d_in[1];
    const float* W1    = (const float*)d_in[2];
    const float* b1    = (const float*)d_in[3];
    const float* W2    = (const float*)d_in[4];
    const float* b2    = (const float*)d_in[5];

    float* out = (float*)d_out;                    // [B,K,C] = 262144 floats
    float* s   = out + (size_t)BB * KK * CC;       // [N,K]   = 3200000 floats

    int*            bounds = (int*)d_ws;                           // 65 ints
    unsigned short* w1f    = (unsigned short*)((char*)d_ws + 1024);   // 64 KB
    float*          part   = (float*)((char*)d_ws + 1024 + 65536);

    int nslices = 32;                              // 32 MB of partials
    while (nslices > 8 &&
           ws_size < 1024 + 65536 + (size_t)BB * nslices * KK * CC * 4)
        nslices >>= 1;

    hp_prep<<<8, 256, 0, stream>>>(batch, W1, bounds, w1f);
    hp_mlp<<<NN / 32, 256, 0, stream>>>(x, w1f, b1, W2, b2, s);
    hp_pool<<<BB * nslices, 256, 0, stream>>>(x, s, bounds, part, nslices);
    hp_reduce<<<BB * KK * CC / (256 * 4), 256, 0, stream>>>(part, out, nslices);
}

// Round 8
// 152.083 us; speedup vs baseline: 1.6995x; 1.2560x over previous
//
#include <hip/hip_runtime.h>
#include <hip/hip_bf16.h>

#define NN 100000
#define CC 128
#define KK 32
#define BB 64

typedef __bf16 bf16x8 __attribute__((ext_vector_type(8)));
typedef float  f32x4  __attribute__((ext_vector_type(4)));

__device__ __forceinline__ unsigned short f2bf(float v) {       // RNE bf16
    union { float f; unsigned u; } a; a.f = v;
    unsigned r = a.u + 0x7FFF + ((a.u >> 16) & 1);
    return (unsigned short)(r >> 16);
}
__device__ __forceinline__ float bf2f(unsigned short h) {
    union { unsigned u; float f; } a; a.u = ((unsigned)h) << 16;
    return a.f;
}
// unpack 8 uints (hi|lo<<16) -> two bf16x8 (low halves, high halves)
__device__ __forceinline__ void unpack_hilo(uint4 a, uint4 b,
                                            bf16x8& hi8, bf16x8& lo8) {
    union { uint4 v[2]; unsigned short s[16]; } U;
    U.v[0] = a; U.v[1] = b;
    union { unsigned short s[8]; bf16x8 v; } H, L;
    #pragma unroll
    for (int j = 0; j < 8; ++j) { H.s[j] = U.s[2 * j]; L.s[j] = U.s[2 * j + 1]; }
    hi8 = H.v; lo8 = L.v;
}

// ---------------------------------------------------------------------------
// Kernel 1 (prep): bounds + W1 & W2 -> bf16 hi/lo MFMA B-fragments.
// w1f[split 2][kt 4][nt 8][lane 64][j 8]:
//   (kt,nt,lane,j) = W1[kt*32 + (lane>>4)*8 + j][nt*16 + (lane&15)]
// w2f[split 2][kt 4][nt 2][lane 64][j 8]:
//   (kt,nt,lane,j) = W2[kt*32 + (lane>>4)*8 + j][nt*16 + (lane&15)]
// 8 blocks x 256 threads.
// ---------------------------------------------------------------------------
__global__ __launch_bounds__(256) void hp_prep(const int* __restrict__ batch,
                                               const float* __restrict__ W1,
                                               const float* __restrict__ W2,
                                               int* __restrict__ bounds,
                                               unsigned short* __restrict__ w1f,
                                               unsigned short* __restrict__ w2f) {
    if (blockIdx.x == 0 && threadIdx.x <= BB) {
        const int b = threadIdx.x;
        int lo = 0, hi = NN;
        while (lo < hi) {
            const int mid = (lo + hi) >> 1;
            if (batch[mid] < b) lo = mid + 1; else hi = mid;
        }
        bounds[b] = lo;
    }
    const int t = blockIdx.x * 256 + threadIdx.x;
    for (int idx = t; idx < 16384; idx += 2048) {
        const int j    = idx & 7;
        const int lane = (idx >> 3) & 63;
        const int nt   = (idx >> 9) & 7;
        const int kt   = idx >> 12;
        const int k = kt * 32 + (lane >> 4) * 8 + j;
        const int n = nt * 16 + (lane & 15);
        const float w = W1[k * CC + n];
        const unsigned short h = f2bf(w);
        w1f[idx]         = h;
        w1f[16384 + idx] = f2bf(w - bf2f(h));
    }
    for (int idx = t; idx < 4096; idx += 2048) {
        const int j    = idx & 7;
        const int lane = (idx >> 3) & 63;
        const int nt   = (idx >> 9) & 1;
        const int kt   = idx >> 10;
        const int k = kt * 32 + (lane >> 4) * 8 + j;
        const int n = nt * 16 + (lane & 15);
        const float w = W2[k * KK + n];
        const unsigned short h = f2bf(w);
        w2f[idx]        = h;
        w2f[4096 + idx] = f2bf(w - bf2f(h));
    }
}

// ---------------------------------------------------------------------------
// Kernel 2: h = relu(x@W1+b1) and s = softmax(h@W2+b2), BOTH via split-bf16
// MFMA. Block = 32 nodes (3125 blocks), 256 threads, 4 waves.
//  stage:   x -> bf16 hi/lo A-frags in LDS.
//  phase 1: wave w owns n-tiles {2w,2w+1}: 48 mfma_16x16x32_bf16
//           (xh*wh + xl*wh + xh*wl); W1 frags coalesced from global (L2-hot).
//  epilog:  h packed as (hi | lo<<16) uint -> hs16[node][132] (overlays xa).
//  phase 2: wave (mt=w&1, nt=w>>1): A-frags of h via 2 ds_read_b128 + perm
//           unpack; W2 frags from global (16 KB, L2-hot); 12 MFMA; D-frag
//           logits -> lgT[node][k].  (kills round-7's 512 KB/block L1 storm)
//  phase 3: softmax, 2-round LDS combine; every lane stores 4 s values.
// LDS: max(xa 16K, hs16 16.5K) + lgT 4.5K + red 1K = 22 KB -> 6 blocks/CU.
// ---------------------------------------------------------------------------
__global__ __launch_bounds__(256, 6) void hp_mlp(
    const float* __restrict__ x,
    const unsigned short* __restrict__ w1f,
    const unsigned short* __restrict__ w2f,
    const float* __restrict__ b1,
    const float* __restrict__ b2,
    float* __restrict__ s_out)
{
    __shared__ __align__(16) char uni[16896];     // xa (16384 B) / hs16 (16896 B)
    __shared__ float lgT[32][36];                 // [node][k], pad 36
    __shared__ float redm[4][32];
    __shared__ float reds[4][32];

    unsigned short* xa   = (unsigned short*)uni;  // [split][q=mt*4+kt][lane][8]
    unsigned int*   hs16 = (unsigned int*)uni;    // [node][132]: hi | lo<<16

    const int t    = threadIdx.x;
    const int wave = __builtin_amdgcn_readfirstlane(t >> 6);
    const int lane = t & 63;
    const int base = blockIdx.x * 32;

    // ---- stage x -> bf16 hi/lo A-frags (thread does mt = 0,1; kt = wave) ----
    #pragma unroll
    for (int mt = 0; mt < 2; ++mt) {
        const int q  = mt * 4 + wave;
        const int n  = base + mt * 16 + (lane & 15);
        const int ck = wave * 32 + (lane >> 4) * 8;
        const float4 va = *(const float4*)(x + (size_t)n * CC + ck);
        const float4 vb = *(const float4*)(x + (size_t)n * CC + ck + 4);
        const float v[8] = {va.x, va.y, va.z, va.w, vb.x, vb.y, vb.z, vb.w};
        unsigned short hi[8], lo[8];
        #pragma unroll
        for (int j = 0; j < 8; ++j) {
            hi[j] = f2bf(v[j]);
            lo[j] = f2bf(v[j] - bf2f(hi[j]));
        }
        unsigned short* d0 = xa + (q * 64 + lane) * 8;
        unsigned short* d1 = d0 + 4096;
        *(ushort4*)(d0)     = make_ushort4(hi[0], hi[1], hi[2], hi[3]);
        *(ushort4*)(d0 + 4) = make_ushort4(hi[4], hi[5], hi[6], hi[7]);
        *(ushort4*)(d1)     = make_ushort4(lo[0], lo[1], lo[2], lo[3]);
        *(ushort4*)(d1 + 4) = make_ushort4(lo[4], lo[5], lo[6], lo[7]);
    }
    __syncthreads();

    // ---- phase 1: MFMA; wave owns n-tiles 2w, 2w+1 ----
    f32x4 acc[2][2];
    #pragma unroll
    for (int mt = 0; mt < 2; ++mt)
        #pragma unroll
        for (int nl = 0; nl < 2; ++nl)
            acc[mt][nl] = (f32x4){0.f, 0.f, 0.f, 0.f};

    #pragma unroll
    for (int kt = 0; kt < 4; ++kt) {
        bf16x8 ah[2], al[2];
        #pragma unroll
        for (int mt = 0; mt < 2; ++mt) {
            ah[mt] = *(const bf16x8*)(xa + ((mt * 4 + kt) * 64 + lane) * 8);
            al[mt] = *(const bf16x8*)(xa + 4096 + ((mt * 4 + kt) * 64 + lane) * 8);
        }
        #pragma unroll
        for (int nl = 0; nl < 2; ++nl) {
            const int nt = 2 * wave + nl;
            const bf16x8 wh = *(const bf16x8*)(w1f + ((kt * 8 + nt) * 64 + lane) * 8);
            const bf16x8 wl = *(const bf16x8*)(w1f + 16384 + ((kt * 8 + nt) * 64 + lane) * 8);
            #pragma unroll
            for (int mt = 0; mt < 2; ++mt) {
                acc[mt][nl] = __builtin_amdgcn_mfma_f32_16x16x32_bf16(ah[mt], wh, acc[mt][nl], 0, 0, 0);
                acc[mt][nl] = __builtin_amdgcn_mfma_f32_16x16x32_bf16(al[mt], wh, acc[mt][nl], 0, 0, 0);
                acc[mt][nl] = __builtin_amdgcn_mfma_f32_16x16x32_bf16(ah[mt], wl, acc[mt][nl], 0, 0, 0);
            }
        }
    }
    __syncthreads();                               // xa dead; hs16 overlays

    // ---- epilogue: bias+relu, pack hi|lo<<16 -> hs16[node][132] ----
    #pragma unroll
    for (int nl = 0; nl < 2; ++nl) {
        const int c = (2 * wave + nl) * 16 + (lane & 15);
        const float bv = b1[c];
        #pragma unroll
        for (int mt = 0; mt < 2; ++mt)
            #pragma unroll
            for (int r = 0; r < 4; ++r) {
                const int node = mt * 16 + (lane >> 4) * 4 + r;
                const float h = fmaxf(acc[mt][nl][r] + bv, 0.f);
                const unsigned short hi = f2bf(h);
                const unsigned short lo = f2bf(h - bf2f(hi));
                hs16[node * 132 + c] = (unsigned)hi | ((unsigned)lo << 16);
            }
    }
    __syncthreads();

    // ---- phase 2: logits via MFMA; wave = (mt2 = w&1, nt2 = w>>1) ----
    {
        const int mt2 = wave & 1, nt2 = wave >> 1;
        f32x4 dacc = (f32x4){0.f, 0.f, 0.f, 0.f};
        #pragma unroll
        for (int kt = 0; kt < 4; ++kt) {
            const unsigned* hp = hs16 + (mt2 * 16 + (lane & 15)) * 132
                                      + kt * 32 + (lane >> 4) * 8;
            const uint4 u0 = *(const uint4*)hp;
            const uint4 u1 = *(const uint4*)(hp + 4);
            bf16x8 ah, al;
            unpack_hilo(u0, u1, ah, al);
            const bf16x8 wh = *(const bf16x8*)(w2f + ((kt * 2 + nt2) * 64 + lane) * 8);
            const bf16x8 wl = *(const bf16x8*)(w2f + 4096 + ((kt * 2 + nt2) * 64 + lane) * 8);
            dacc = __builtin_amdgcn_mfma_f32_16x16x32_bf16(ah, wh, dacc, 0, 0, 0);
            dacc = __builtin_amdgcn_mfma_f32_16x16x32_bf16(al, wh, dacc, 0, 0, 0);
            dacc = __builtin_amdgcn_mfma_f32_16x16x32_bf16(ah, wl, dacc, 0, 0, 0);
        }
        const int kcol = nt2 * 16 + (lane & 15);
        #pragma unroll
        for (int r = 0; r < 4; ++r) {
            const int node = mt2 * 16 + (lane >> 4) * 4 + r;
            lgT[node][kcol] = dacc[r];
        }
    }
    __syncthreads();

    // ---- phase 3: softmax (2-round LDS combine), all lanes store ----
    const int node = lane & 31;
    const int koff = ((lane >> 5) << 4) + wave * 4;
    const float4 bv2 = *(const float4*)(b2 + koff);
    const float4 lv  = *(const float4*)&lgT[node][koff];
    float lg[4] = {lv.x + bv2.x, lv.y + bv2.y, lv.z + bv2.z, lv.w + bv2.w};

    float m = fmaxf(fmaxf(lg[0], lg[1]), fmaxf(lg[2], lg[3]));
    m = fmaxf(m, __shfl_xor(m, 32));
    if (lane < 32) redm[wave][lane] = m;
    __syncthreads();
    const float M = fmaxf(fmaxf(redm[0][node], redm[1][node]),
                          fmaxf(redm[2][node], redm[3][node]));
    const float e0 = __expf(lg[0] - M);
    const float e1 = __expf(lg[1] - M);
    const float e2 = __expf(lg[2] - M);
    const float e3 = __expf(lg[3] - M);
    float sp = (e0 + e1) + (e2 + e3);
    sp += __shfl_xor(sp, 32);
    if (lane < 32) reds[wave][lane] = sp;
    __syncthreads();
    const float S = (reds[0][node] + reds[1][node]) + (reds[2][node] + reds[3][node]);
    const float inv = 1.f / S;
    *(float4*)(s_out + (size_t)(base + node) * KK + koff) =
        make_float4(e0 * inv, e1 * inv, e2 * inv, e3 * inv);
}

// ---------------------------------------------------------------------------
// Kernel 3: partial pooling, panel-staged (unchanged from round 7).
// ---------------------------------------------------------------------------
__global__ __launch_bounds__(256, 8) void hp_pool(
    const float* __restrict__ x,
    const float* __restrict__ s,
    const int* __restrict__ bounds,
    float* __restrict__ part,
    int nslices)
{
    __shared__ float xs[8][CC];
    __shared__ float ss[8][36];

    const int b = blockIdx.x / nslices;
    const int p = blockIdx.x - b * nslices;
    const int t = threadIdx.x;

    const int gs  = bounds[b];
    const int cnt = bounds[b + 1] - gs;
    const int n0  = gs + (int)(((long long)cnt * p) / nslices);
    const int n1  = gs + (int)(((long long)cnt * (p + 1)) / nslices);

    const int k0 = (t >> 5) * 4;
    const int c0 = (t & 31) * 4;

    float a4[4][4] = {{0.f}};

    for (int nb = n0; nb < n1; nb += 8) {
        const int m = min(8, n1 - nb);
        __syncthreads();
        {
            const int r = t >> 5, cf = t & 31;
            if (r < m)
                *(float4*)&xs[r][cf * 4] = ((const float4*)x)[(size_t)(nb + r) * 32 + cf];
            if (t < 64) {
                const int r2 = t >> 3, kf = t & 7;
                if (r2 < m)
                    *(float4*)&ss[r2][kf * 4] = ((const float4*)s)[(size_t)(nb + r2) * 8 + kf];
            }
        }
        __syncthreads();

        for (int i = 0; i < m; ++i) {
            const float4 xv = *(const float4*)&xs[i][c0];
            const float4 sv = *(const float4*)&ss[i][k0];
            a4[0][0] = fmaf(sv.x, xv.x, a4[0][0]); a4[0][1] = fmaf(sv.x, xv.y, a4[0][1]);
            a4[0][2] = fmaf(sv.x, xv.z, a4[0][2]); a4[0][3] = fmaf(sv.x, xv.w, a4[0][3]);
            a4[1][0] = fmaf(sv.y, xv.x, a4[1][0]); a4[1][1] = fmaf(sv.y, xv.y, a4[1][1]);
            a4[1][2] = fmaf(sv.y, xv.z, a4[1][2]); a4[1][3] = fmaf(sv.y, xv.w, a4[1][3]);
            a4[2][0] = fmaf(sv.z, xv.x, a4[2][0]); a4[2][1] = fmaf(sv.z, xv.y, a4[2][1]);
            a4[2][2] = fmaf(sv.z, xv.z, a4[2][2]); a4[2][3] = fmaf(sv.z, xv.w, a4[2][3]);
            a4[3][0] = fmaf(sv.w, xv.x, a4[3][0]); a4[3][1] = fmaf(sv.w, xv.y, a4[3][1]);
            a4[3][2] = fmaf(sv.w, xv.z, a4[3][2]); a4[3][3] = fmaf(sv.w, xv.w, a4[3][3]);
        }
    }

    float* op = part + (size_t)blockIdx.x * KK * CC;
    #pragma unroll
    for (int a = 0; a < 4; ++a)
        *(float4*)&op[(k0 + a) * CC + c0] =
            make_float4(a4[a][0], a4[a][1], a4[a][2], a4[a][3]);
}

// ---------------------------------------------------------------------------
// Kernel 4: out[b] = sum of the nslices partial tiles.
// ---------------------------------------------------------------------------
__global__ __launch_bounds__(256) void hp_reduce(const float* __restrict__ part,
                                                 float* __restrict__ out,
                                                 int nslices) {
    const int i = (blockIdx.x * 256 + threadIdx.x) * 4;
    if (i < BB * KK * CC) {
        const int b = i >> 12;
        const int j = i & 4095;
        const float* pp = part + (size_t)b * nslices * 4096 + j;
        float4 r = make_float4(0.f, 0.f, 0.f, 0.f);
        for (int q = 0; q < nslices; ++q) {
            const float4 v = *(const float4*)(pp + (size_t)q * 4096);
            r.x += v.x; r.y += v.y; r.z += v.z; r.w += v.w;
        }
        *(float4*)(out + i) = r;
    }
}

// ---------------------------------------------------------------------------
extern "C" void kernel_launch(void* const* d_in, const int* in_sizes, int n_in,
                              void* d_out, int out_size, void* d_ws, size_t ws_size,
                              hipStream_t stream) {
    const float* x     = (const float*)d_in[0];
    const int*   batch = (const int*)d_in[1];
    const float* W1    = (const float*)d_in[2];
    const float* b1    = (const float*)d_in[3];
    const float* W2    = (const float*)d_in[4];
    const float* b2    = (const float*)d_in[5];

    float* out = (float*)d_out;                    // [B,K,C] = 262144 floats
    float* s   = out + (size_t)BB * KK * CC;       // [N,K]   = 3200000 floats

    int*            bounds = (int*)d_ws;                               // 512 B
    unsigned short* w1f    = (unsigned short*)((char*)d_ws + 1024);    // 64 KB
    unsigned short* w2f    = (unsigned short*)((char*)d_ws + 66560);   // 16 KB
    float*          part   = (float*)((char*)d_ws + 82944);

    int nslices = 32;                              // 32 MB of partials
    while (nslices > 8 &&
           ws_size < 82944 + (size_t)BB * nslices * KK * CC * 4)
        nslices >>= 1;

    hp_prep<<<8, 256, 0, stream>>>(batch, W1, W2, bounds, w1f, w2f);
    hp_mlp<<<NN / 32, 256, 0, stream>>>(x, w1f, w2f, b1, b2, s);
    hp_pool<<<BB * nslices, 256, 0, stream>>>(x, s, bounds, part, nslices);
    hp_reduce<<<BB * KK * CC / (256 * 4), 256, 0, stream>>>(part, out, nslices);
}

// Round 9
// 135.369 us; speedup vs baseline: 1.9093x; 1.1235x over previous
//
#include <hip/hip_runtime.h>
#include <hip/hip_bf16.h>

#define NN 100000
#define CC 128
#define KK 32
#define BB 64
#define PS 16          // pool slices per graph

typedef __bf16 bf16x8 __attribute__((ext_vector_type(8)));
typedef float  f32x4  __attribute__((ext_vector_type(4)));

__device__ __forceinline__ unsigned short f2bf(float v) {       // RNE bf16
    union { float f; unsigned u; } a; a.f = v;
    unsigned r = a.u + 0x7FFF + ((a.u >> 16) & 1);
    return (unsigned short)(r >> 16);
}
__device__ __forceinline__ float bf2f(unsigned short h) {
    union { unsigned u; float f; } a; a.u = ((unsigned)h) << 16;
    return a.f;
}
// unpack 8 uints (hi|lo<<16) -> two bf16x8
__device__ __forceinline__ void unpack_hilo(uint4 a, uint4 b,
                                            bf16x8& hi8, bf16x8& lo8) {
    union { uint4 v[2]; unsigned short s[16]; } U;
    U.v[0] = a; U.v[1] = b;
    union { unsigned short s[8]; bf16x8 v; } H, L;
    #pragma unroll
    for (int j = 0; j < 8; ++j) { H.s[j] = U.s[2 * j]; L.s[j] = U.s[2 * j + 1]; }
    hi8 = H.v; lo8 = L.v;
}

// ---------------------------------------------------------------------------
// Kernel 1 (prep): bounds + W1 & W2 -> bf16 hi/lo MFMA B-fragments.
// ---------------------------------------------------------------------------
__global__ __launch_bounds__(256) void hp_prep(const int* __restrict__ batch,
                                               const float* __restrict__ W1,
                                               const float* __restrict__ W2,
                                               int* __restrict__ bounds,
                                               unsigned short* __restrict__ w1f,
                                               unsigned short* __restrict__ w2f) {
    if (blockIdx.x == 0 && threadIdx.x <= BB) {
        const int b = threadIdx.x;
        int lo = 0, hi = NN;
        while (lo < hi) {
            const int mid = (lo + hi) >> 1;
            if (batch[mid] < b) lo = mid + 1; else hi = mid;
        }
        bounds[b] = lo;
    }
    const int t = blockIdx.x * 256 + threadIdx.x;
    for (int idx = t; idx < 16384; idx += 2048) {
        const int j    = idx & 7;
        const int lane = (idx >> 3) & 63;
        const int nt   = (idx >> 9) & 7;
        const int kt   = idx >> 12;
        const int k = kt * 32 + (lane >> 4) * 8 + j;
        const int n = nt * 16 + (lane & 15);
        const float w = W1[k * CC + n];
        const unsigned short h = f2bf(w);
        w1f[idx]         = h;
        w1f[16384 + idx] = f2bf(w - bf2f(h));
    }
    for (int idx = t; idx < 4096; idx += 2048) {
        const int j    = idx & 7;
        const int lane = (idx >> 3) & 63;
        const int nt   = (idx >> 9) & 1;
        const int kt   = idx >> 10;
        const int k = kt * 32 + (lane >> 4) * 8 + j;
        const int n = nt * 16 + (lane & 15);
        const float w = W2[k * KK + n];
        const unsigned short h = f2bf(w);
        w2f[idx]        = h;
        w2f[4096 + idx] = f2bf(w - bf2f(h));
    }
}

// ---------------------------------------------------------------------------
// Kernel 2: MLP (both layers split-bf16 MFMA) + softmax; also emits pool
// operand fragments:
//   xb[chunk 3125][ct 8][lane 64][j 8] = bf16 x[ch*32+(lane>>4)*8+j][ct*16+(lane&15)]
//   sb[chunk 3125][mt 2][lane 64][j 8] = bf16 s[ch*32+(lane>>4)*8+j][mt*16+(lane&15)]
// Block = 32 nodes = one chunk (3125 blocks), 256 threads, 4 waves.
// ---------------------------------------------------------------------------
__global__ __launch_bounds__(256, 6) void hp_mlp(
    const float* __restrict__ x,
    const unsigned short* __restrict__ w1f,
    const unsigned short* __restrict__ w2f,
    const float* __restrict__ b1,
    const float* __restrict__ b2,
    float* __restrict__ s_out,
    unsigned short* __restrict__ xb,
    unsigned short* __restrict__ sb)
{
    __shared__ __align__(16) char uni[16896];     // xa (16384 B) / hs16 (16896 B)
    __shared__ float lgT[32][36];                 // [node][k] logits, then s
    __shared__ float redm[4][32];
    __shared__ float reds[4][32];

    unsigned short* xa   = (unsigned short*)uni;  // [split][q=mt*4+kt][lane][8]
    unsigned int*   hs16 = (unsigned int*)uni;    // [node][132]: hi | lo<<16

    const int t    = threadIdx.x;
    const int wave = __builtin_amdgcn_readfirstlane(t >> 6);
    const int lane = t & 63;
    const int base = blockIdx.x * 32;

    // ---- stage x -> bf16 hi/lo A-frags (thread does mt = 0,1; kt = wave) ----
    #pragma unroll
    for (int mt = 0; mt < 2; ++mt) {
        const int q  = mt * 4 + wave;
        const int n  = base + mt * 16 + (lane & 15);
        const int ck = wave * 32 + (lane >> 4) * 8;
        const float4 va = *(const float4*)(x + (size_t)n * CC + ck);
        const float4 vb = *(const float4*)(x + (size_t)n * CC + ck + 4);
        const float v[8] = {va.x, va.y, va.z, va.w, vb.x, vb.y, vb.z, vb.w};
        unsigned short hi[8], lo[8];
        #pragma unroll
        for (int j = 0; j < 8; ++j) {
            hi[j] = f2bf(v[j]);
            lo[j] = f2bf(v[j] - bf2f(hi[j]));
        }
        unsigned short* d0 = xa + (q * 64 + lane) * 8;
        unsigned short* d1 = d0 + 4096;
        *(ushort4*)(d0)     = make_ushort4(hi[0], hi[1], hi[2], hi[3]);
        *(ushort4*)(d0 + 4) = make_ushort4(hi[4], hi[5], hi[6], hi[7]);
        *(ushort4*)(d1)     = make_ushort4(lo[0], lo[1], lo[2], lo[3]);
        *(ushort4*)(d1 + 4) = make_ushort4(lo[4], lo[5], lo[6], lo[7]);
    }

    // ---- emit xb pool B-frags (x re-read is L1/L2-hot; quarter-wave 64B) ----
    #pragma unroll
    for (int cc = 0; cc < 2; ++cc) {
        const int ct = wave * 2 + cc;
        const int c  = ct * 16 + (lane & 15);
        const int nb = base + (lane >> 4) * 8;
        unsigned short hb[8];
        #pragma unroll
        for (int j = 0; j < 8; ++j)
            hb[j] = f2bf(x[(size_t)(nb + j) * CC + c]);
        unsigned short* dp = xb + ((size_t)(blockIdx.x * 8 + ct) * 64 + lane) * 8;
        *(ushort4*)(dp)     = make_ushort4(hb[0], hb[1], hb[2], hb[3]);
        *(ushort4*)(dp + 4) = make_ushort4(hb[4], hb[5], hb[6], hb[7]);
    }
    __syncthreads();

    // ---- phase 1: MFMA; wave owns n-tiles 2w, 2w+1 ----
    f32x4 acc[2][2];
    #pragma unroll
    for (int mt = 0; mt < 2; ++mt)
        #pragma unroll
        for (int nl = 0; nl < 2; ++nl)
            acc[mt][nl] = (f32x4){0.f, 0.f, 0.f, 0.f};

    #pragma unroll
    for (int kt = 0; kt < 4; ++kt) {
        bf16x8 ah[2], al[2];
        #pragma unroll
        for (int mt = 0; mt < 2; ++mt) {
            ah[mt] = *(const bf16x8*)(xa + ((mt * 4 + kt) * 64 + lane) * 8);
            al[mt] = *(const bf16x8*)(xa + 4096 + ((mt * 4 + kt) * 64 + lane) * 8);
        }
        #pragma unroll
        for (int nl = 0; nl < 2; ++nl) {
            const int nt = 2 * wave + nl;
            const bf16x8 wh = *(const bf16x8*)(w1f + ((kt * 8 + nt) * 64 + lane) * 8);
            const bf16x8 wl = *(const bf16x8*)(w1f + 16384 + ((kt * 8 + nt) * 64 + lane) * 8);
            #pragma unroll
            for (int mt = 0; mt < 2; ++mt) {
                acc[mt][nl] = __builtin_amdgcn_mfma_f32_16x16x32_bf16(ah[mt], wh, acc[mt][nl], 0, 0, 0);
                acc[mt][nl] = __builtin_amdgcn_mfma_f32_16x16x32_bf16(al[mt], wh, acc[mt][nl], 0, 0, 0);
                acc[mt][nl] = __builtin_amdgcn_mfma_f32_16x16x32_bf16(ah[mt], wl, acc[mt][nl], 0, 0, 0);
            }
        }
    }
    __syncthreads();                               // xa dead; hs16 overlays

    // ---- epilogue: bias+relu, pack hi|lo<<16 -> hs16[node][132] ----
    #pragma unroll
    for (int nl = 0; nl < 2; ++nl) {
        const int c = (2 * wave + nl) * 16 + (lane & 15);
        const float bv = b1[c];
        #pragma unroll
        for (int mt = 0; mt < 2; ++mt)
            #pragma unroll
            for (int r = 0; r < 4; ++r) {
                const int node = mt * 16 + (lane >> 4) * 4 + r;
                const float h = fmaxf(acc[mt][nl][r] + bv, 0.f);
                const unsigned short hi = f2bf(h);
                const unsigned short lo = f2bf(h - bf2f(hi));
                hs16[node * 132 + c] = (unsigned)hi | ((unsigned)lo << 16);
            }
    }
    __syncthreads();

    // ---- phase 2: logits via MFMA; wave = (mt2 = w&1, nt2 = w>>1) ----
    {
        const int mt2 = wave & 1, nt2 = wave >> 1;
        f32x4 dacc = (f32x4){0.f, 0.f, 0.f, 0.f};
        #pragma unroll
        for (int kt = 0; kt < 4; ++kt) {
            const unsigned* hp = hs16 + (mt2 * 16 + (lane & 15)) * 132
                                      + kt * 32 + (lane >> 4) * 8;
            const uint4 u0 = *(const uint4*)hp;
            const uint4 u1 = *(const uint4*)(hp + 4);
            bf16x8 ah, al;
            unpack_hilo(u0, u1, ah, al);
            const bf16x8 wh = *(const bf16x8*)(w2f + ((kt * 2 + nt2) * 64 + lane) * 8);
            const bf16x8 wl = *(const bf16x8*)(w2f + 4096 + ((kt * 2 + nt2) * 64 + lane) * 8);
            dacc = __builtin_amdgcn_mfma_f32_16x16x32_bf16(ah, wh, dacc, 0, 0, 0);
            dacc = __builtin_amdgcn_mfma_f32_16x16x32_bf16(al, wh, dacc, 0, 0, 0);
            dacc = __builtin_amdgcn_mfma_f32_16x16x32_bf16(ah, wl, dacc, 0, 0, 0);
        }
        const int kcol = nt2 * 16 + (lane & 15);
        #pragma unroll
        for (int r = 0; r < 4; ++r) {
            const int node = mt2 * 16 + (lane >> 4) * 4 + r;
            lgT[node][kcol] = dacc[r];
        }
    }
    __syncthreads();

    // ---- phase 3: softmax (2-round LDS combine) ----
    const int node = lane & 31;
    const int koff = ((lane >> 5) << 4) + wave * 4;
    const float4 bv2 = *(const float4*)(b2 + koff);
    const float4 lv  = *(const float4*)&lgT[node][koff];
    float lg[4] = {lv.x + bv2.x, lv.y + bv2.y, lv.z + bv2.z, lv.w + bv2.w};

    float m = fmaxf(fmaxf(lg[0], lg[1]), fmaxf(lg[2], lg[3]));
    m = fmaxf(m, __shfl_xor(m, 32));
    if (lane < 32) redm[wave][lane] = m;
    __syncthreads();
    const float M = fmaxf(fmaxf(redm[0][node], redm[1][node]),
                          fmaxf(redm[2][node], redm[3][node]));
    const float e0 = __expf(lg[0] - M);
    const float e1 = __expf(lg[1] - M);
    const float e2 = __expf(lg[2] - M);
    const float e3 = __expf(lg[3] - M);
    float sp = (e0 + e1) + (e2 + e3);
    sp += __shfl_xor(sp, 32);
    if (lane < 32) reds[wave][lane] = sp;
    __syncthreads();
    const float S = (reds[0][node] + reds[1][node]) + (reds[2][node] + reds[3][node]);
    const float inv = 1.f / S;
    const float4 s4 = make_float4(e0 * inv, e1 * inv, e2 * inv, e3 * inv);
    *(float4*)(s_out + (size_t)(base + node) * KK + koff) = s4;
    *(float4*)&lgT[node][koff] = s4;               // normalized s for sb pack
    __syncthreads();

    // ---- emit sb pool A-frags (waves 0,1: mt = wave) ----
    if (wave < 2) {
        const int k  = wave * 16 + (lane & 15);
        const int r0 = (lane >> 4) * 8;
        unsigned short v[8];
        #pragma unroll
        for (int j = 0; j < 8; ++j)
            v[j] = f2bf(lgT[r0 + j][k]);
        unsigned short* dp = sb + ((size_t)(blockIdx.x * 2 + wave) * 64 + lane) * 8;
        *(ushort4*)(dp)     = make_ushort4(v[0], v[1], v[2], v[3]);
        *(ushort4*)(dp + 4) = make_ushort4(v[4], v[5], v[6], v[7]);
    }
}

// ---------------------------------------------------------------------------
// Kernel 3: pooling via MFMA on pre-built frags. Block = (graph b, slice p);
// 4 waves: wave = (mt = w&1, chalf = w>>1). Per 32-node chunk per wave:
// 1 sb A-frag (boundary-masked) + 4 xb B-frags + 4 MFMA. Zero LDS/barriers.
// ---------------------------------------------------------------------------
__global__ __launch_bounds__(256) void hp_pool(
    const unsigned short* __restrict__ xb,
    const unsigned short* __restrict__ sb,
    const int* __restrict__ bounds,
    float* __restrict__ part)
{
    const int b = blockIdx.x / PS;
    const int p = blockIdx.x - b * PS;
    const int wave = __builtin_amdgcn_readfirstlane(threadIdx.x >> 6);
    const int lane = threadIdx.x & 63;

    const int gs = bounds[b], ge = bounds[b + 1];
    const int c0g = gs >> 5;
    const int cnt = ((ge + 31) >> 5) - c0g;
    const int ch0 = c0g + (cnt * p) / PS;
    const int ch1 = c0g + (cnt * (p + 1)) / PS;

    const int mt    = wave & 1;
    const int chalf = wave >> 1;
    const int nrow  = (lane >> 4) * 8;

    f32x4 acc[4];
    #pragma unroll
    for (int i = 0; i < 4; ++i) acc[i] = (f32x4){0.f, 0.f, 0.f, 0.f};

    for (int ch = ch0; ch < ch1; ++ch) {
        union { ushort4 u[2]; unsigned short s[8]; bf16x8 v; } A;
        const unsigned short* ap = sb + ((size_t)(ch * 2 + mt) * 64 + lane) * 8;
        A.u[0] = *(const ushort4*)ap;
        A.u[1] = *(const ushort4*)(ap + 4);
        const int nb = ch * 32 + nrow;
        #pragma unroll
        for (int j = 0; j < 8; ++j)
            if (nb + j < gs || nb + j >= ge) A.s[j] = 0;   // mask other graphs
        #pragma unroll
        for (int i = 0; i < 4; ++i) {
            const int ct = chalf * 4 + i;
            const bf16x8 Bv = *(const bf16x8*)(xb + ((size_t)(ch * 8 + ct) * 64 + lane) * 8);
            acc[i] = __builtin_amdgcn_mfma_f32_16x16x32_bf16(A.v, Bv, acc[i], 0, 0, 0);
        }
    }

    float* op = part + (size_t)blockIdx.x * KK * CC;
    #pragma unroll
    for (int i = 0; i < 4; ++i) {
        const int c = (chalf * 4 + i) * 16 + (lane & 15);
        #pragma unroll
        for (int r = 0; r < 4; ++r) {
            const int k = mt * 16 + (lane >> 4) * 4 + r;
            op[k * CC + c] = acc[i][r];
        }
    }
}

// ---------------------------------------------------------------------------
// Kernel 4: out[b] = sum of the PS partial tiles.
// ---------------------------------------------------------------------------
__global__ __launch_bounds__(256) void hp_reduce(const float* __restrict__ part,
                                                 float* __restrict__ out) {
    const int i = (blockIdx.x * 256 + threadIdx.x) * 4;
    if (i < BB * KK * CC) {
        const int b = i >> 12;
        const int j = i & 4095;
        const float* pp = part + (size_t)b * PS * 4096 + j;
        float4 r = make_float4(0.f, 0.f, 0.f, 0.f);
        #pragma unroll 4
        for (int q = 0; q < PS; ++q) {
            const float4 v = *(const float4*)(pp + (size_t)q * 4096);
            r.x += v.x; r.y += v.y; r.z += v.z; r.w += v.w;
        }
        *(float4*)(out + i) = r;
    }
}

// ---------------------------------------------------------------------------
extern "C" void kernel_launch(void* const* d_in, const int* in_sizes, int n_in,
                              void* d_out, int out_size, void* d_ws, size_t ws_size,
                              hipStream_t stream) {
    const float* x     = (const float*)d_in[0];
    const int*   batch = (const int*)d_in[1];
    const float* W1    = (const float*)d_in[2];
    const float* b1    = (const float*)d_in[3];
    const float* W2    = (const float*)d_in[4];
    const float* b2    = (const float*)d_in[5];

    float* out = (float*)d_out;                    // [B,K,C] = 262144 floats
    float* s   = out + (size_t)BB * KK * CC;       // [N,K]   = 3200000 floats

    char* ws = (char*)d_ws;
    int*            bounds = (int*)ws;                          // 512 B
    unsigned short* w1f    = (unsigned short*)(ws + 1024);      // 64 KB
    unsigned short* w2f    = (unsigned short*)(ws + 66560);     // 16 KB
    unsigned short* xb     = (unsigned short*)(ws + 82944);     // 25.6 MB
    unsigned short* sb     = (unsigned short*)(ws + 82944 + 25600000);      // 6.4 MB
    float*          part   = (float*)(ws + 82944 + 25600000 + 6400000);     // 16.8 MB

    hp_prep<<<8, 256, 0, stream>>>(batch, W1, W2, bounds, w1f, w2f);
    hp_mlp<<<NN / 32, 256, 0, stream>>>(x, w1f, w2f, b1, b2, s, xb, sb);
    hp_pool<<<BB * PS, 256, 0, stream>>>(xb, sb, bounds, part);
    hp_reduce<<<BB * KK * CC / (256 * 4), 256, 0, stream>>>(part, out);
}